// Round 4
// baseline (203.479 us; speedup 1.0000x reference)
//
#include <hip/hip_runtime.h>
#include <hip/hip_bf16.h>

typedef short bf16x8 __attribute__((ext_vector_type(8)));
typedef float f32x4 __attribute__((ext_vector_type(4)));

#define B_ROWS 8192
#define DIM 128
#define NCLS 512
#define MMAX 64
#define NSLICE 32
#define NEG_BLOCKS 1024
#define FIN_BLOCKS 32

// gamma * log2(e): logits computed in base-2 throughout
#define G2 369.32993f
#define LN2F 0.69314718056f

// ============ K1: prep =====================================================
// blocks [0,2048): normalize 4 rows each -> PACKED bf16 fragment layout
//   packed 16B-frag index (T,k,lane): (T*4+k)*64 + lane, lane=lg*16+lc
//   holds old chunk (row=T*16+lc, chunk=lg+4k) -> fragment loads in neg_k are
//   fully coalesced (contiguous 1KB per instruction).
// blocks [2048,2560): class c = bid-2048, self-contained positives:
//   wave0 ballot-scans labels -> member list; block re-normalizes member rows
//   (fp32) into LDS; fused dot + lse2_p / lse2_same.
__global__ __launch_bounds__(256) void prep_k(const float* __restrict__ feat,
                                              const int* __restrict__ label,
                                              unsigned int* __restrict__ fbp,
                                              float* __restrict__ lse2_p,
                                              float* __restrict__ lse2_same,
                                              int* __restrict__ ctrl) {
    const int bid = blockIdx.x;
    const int tid = threadIdx.x;
    const int wv = tid >> 6, ln = tid & 63;

    if (bid < 2048) {
        if (bid == 0 && tid < 4) ctrl[tid] = 0;  // done, done2, gsum, gcnt
        const int row = bid * 4 + wv;
        const float2 v = ((const float2*)feat)[row * 64 + ln];
        float ss = v.x * v.x + v.y * v.y;
        #pragma unroll
        for (int d = 1; d < 64; d <<= 1) ss += __shfl_xor(ss, d);
        const float inv = 1.0f / fmaxf(sqrtf(ss), 1e-12f);
        const float x = v.x * inv, y = v.y * inv;
        __hip_bfloat16 hx = __float2bfloat16(x), hy = __float2bfloat16(y);
        const unsigned int ux = *(const unsigned short*)&hx;
        const unsigned int uy = *(const unsigned short*)&hy;
        // lane ln holds row elements 2ln,2ln+1 -> chunk c=ln>>2, dword j=ln&3
        const int T = row >> 4, lc = row & 15, c = ln >> 2, j = ln & 3;
        const int frag16 = (T * 4 + (c >> 2)) * 64 + (c & 3) * 16 + lc;
        fbp[frag16 * 4 + j] = ux | (uy << 16);
        return;
    }

    // ---- positives ----
    const int c = bid - 2048;
    __shared__ int rl[MMAX];
    __shared__ int s_total;
    __shared__ float F[MMAX][DIM + 1];

    if (wv == 0) {
        int base = 0;
        for (int it = 0; it < 32; ++it) {
            const int4 L = ((const int4*)label)[it * 64 + ln];
            const int lv[4] = {L.x, L.y, L.z, L.w};
            #pragma unroll
            for (int j = 0; j < 4; ++j) {
                const bool hit = (lv[j] == c);
                const unsigned long long mask = __ballot(hit);
                const int below = __popcll(mask & ((1ull << ln) - 1ull));
                const int slot = base + below;
                if (hit && slot < MMAX) rl[slot] = (it * 64 + ln) * 4 + j;
                base += __popcll(mask);
            }
        }
        if (ln == 0) s_total = base;
    }
    __syncthreads();
    const int total = s_total;
    const int m = total < MMAX ? total : MMAX;
    if (m == 0) return;
    const bool row_valid = (total >= 2);

    // normalize member rows (fp32 exact) into LDS
    for (int i = wv; i < m; i += 4) {
        const int r = rl[i];
        const float2 v = ((const float2*)feat)[r * 64 + ln];
        float ss = v.x * v.x + v.y * v.y;
        #pragma unroll
        for (int d = 1; d < 64; d <<= 1) ss += __shfl_xor(ss, d);
        const float inv = 1.0f / fmaxf(sqrtf(ss), 1e-12f);
        F[i][2 * ln] = v.x * inv;
        F[i][2 * ln + 1] = v.y * inv;
    }
    __syncthreads();

    for (int i = wv; i < m; i += 4) {
        float s = 0.f;
        if (ln < m) {
            #pragma unroll 8
            for (int k = 0; k < DIM; ++k) s = fmaf(F[i][k], F[ln][k], s);
        }
        const bool act = (ln < m) && (ln != i);
        const float up = 1.25f - s;
        const float lp = act ? G2 * fmaxf(up, 0.f) * (up - 0.5f) : -1e30f;
        const float un = s + 0.25f;
        const float lnn = act ? G2 * fmaxf(un, 0.f) * (un - 0.5f) : -1e30f;
        float Mp = lp, Mn = lnn;
        #pragma unroll
        for (int d = 1; d < 64; d <<= 1) {
            Mp = fmaxf(Mp, __shfl_xor(Mp, d));
            Mn = fmaxf(Mn, __shfl_xor(Mn, d));
        }
        float Sp = act ? __builtin_amdgcn_exp2f(lp - Mp) : 0.f;
        float Sn = act ? __builtin_amdgcn_exp2f(lnn - Mn) : 0.f;
        #pragma unroll
        for (int d = 1; d < 64; d <<= 1) { Sp += __shfl_xor(Sp, d); Sn += __shfl_xor(Sn, d); }
        if (ln == 0) {
            const int row = rl[i];
            lse2_p[row]    = row_valid ? (Mp + __builtin_amdgcn_logf(Sp)) : -1e30f;
            lse2_same[row] = row_valid ? (Mn + __builtin_amdgcn_logf(Sn)) : -1e30f;
        }
    }
}

// ---------------- epilogue for one f32x4 acc --------------------------------
__device__ __forceinline__ void epi4(f32x4 acc, float& M, float& S,
                                     bool diag, int lc, int lg) {
    float u0 = acc[0] + 0.25f; float w0 = fmaf(G2, acc[0], -0.25f * G2);
    float u1 = acc[1] + 0.25f; float w1 = fmaf(G2, acc[1], -0.25f * G2);
    float u2 = acc[2] + 0.25f; float w2 = fmaf(G2, acc[2], -0.25f * G2);
    float u3 = acc[3] + 0.25f; float w3 = fmaf(G2, acc[3], -0.25f * G2);
    float l0 = fmaxf(u0, 0.f) * w0, l1 = fmaxf(u1, 0.f) * w1;
    float l2 = fmaxf(u2, 0.f) * w2, l3 = fmaxf(u3, 0.f) * w3;
    if (diag) {  // wave-uniform: the one diagonal tile
        const int base = lg * 4;
        l0 = (base + 0 == lc) ? -3.0e8f : l0;
        l1 = (base + 1 == lc) ? -3.0e8f : l1;
        l2 = (base + 2 == lc) ? -3.0e8f : l2;
        l3 = (base + 3 == lc) ? -3.0e8f : l3;
    }
    const float gm = fmaxf(fmaxf(l0, l1), fmaxf(l2, l3));
    // skip tiles that can't contribute > 2^-25 relative (wave-coherent)
    if (__any(gm > M - 25.f)) {
        const float Mn = fmaxf(M, gm);
        const float r  = __builtin_amdgcn_exp2f(M - Mn);
        const float e0 = __builtin_amdgcn_exp2f(l0 - Mn);
        const float e1 = __builtin_amdgcn_exp2f(l1 - Mn);
        const float e2 = __builtin_amdgcn_exp2f(l2 - Mn);
        const float e3 = __builtin_amdgcn_exp2f(l3 - Mn);
        S = fmaf(S, r, e0) + e1 + e2 + e3;
        M = Mn;
    }
}

// ============ K2: neg GEMM-LSE + ticket-fused finalize ======================
__global__ __launch_bounds__(256, 4) void neg_k(const unsigned short* __restrict__ fb_,
                                                const float* __restrict__ lse2_p,
                                                const float* __restrict__ lse2_same,
                                                float* __restrict__ partials,
                                                int* __restrict__ ctrl,
                                                float* __restrict__ out) {
    const int bid = blockIdx.x;
    const int tid = threadIdx.x;
    const int wv = tid >> 6, ln = tid & 63;
    const int lc = ln & 15, lg = ln >> 4;
    const int slice = bid & 31, mblk = bid >> 5;
    const int mb = mblk * 256 + wv * 64;
    const int mbT = mb >> 4;
    const bf16x8* pk = (const bf16x8*)fb_;
    __shared__ int s_ticket;
    __shared__ float wsum[4];
    __shared__ int wcnt[4];

    bf16x8 a[4][4];
    #pragma unroll
    for (int mi = 0; mi < 4; ++mi)
        #pragma unroll
        for (int k = 0; k < 4; ++k)
            a[mi][k] = pk[((mbT + mi) * 4 + k) * 64 + ln];

    float M[4], S[4];
    #pragma unroll
    for (int mi = 0; mi < 4; ++mi) { M[mi] = -1e30f; S[mi] = 0.f; }

    const int nT0 = slice * 16;
    bf16x8 bA[4], bB[4];

    #define LOADB(dst, nT) { \
        _Pragma("unroll") \
        for (int k = 0; k < 4; ++k) dst[k] = pk[((nT) * 4 + k) * 64 + ln]; }

    #define STEP(bR, nT) { \
        f32x4 acc[4]; \
        _Pragma("unroll") \
        for (int mi = 0; mi < 4; ++mi) acc[mi] = (f32x4){0.f, 0.f, 0.f, 0.f}; \
        _Pragma("unroll") \
        for (int k = 0; k < 4; ++k) { \
            _Pragma("unroll") \
            for (int mi = 0; mi < 4; ++mi) \
                acc[mi] = __builtin_amdgcn_mfma_f32_16x16x32_bf16(bR[k], a[mi][k], acc[mi], 0, 0, 0); \
        } \
        _Pragma("unroll") \
        for (int mi = 0; mi < 4; ++mi) \
            epi4(acc[mi], M[mi], S[mi], (nT) * 16 == mb + mi * 16, lc, lg); }

    LOADB(bA, nT0);
    #pragma unroll 1
    for (int t = 0; t < 16; t += 2) {
        LOADB(bB, nT0 + t + 1);
        STEP(bA, nT0 + t);
        if (t + 2 < 16) LOADB(bA, nT0 + t + 2);
        STEP(bB, nT0 + t + 1);
    }
    #undef LOADB
    #undef STEP

    // merge lane groups (lanes l, l^16, l^32, l^48 hold disjoint n-subsets)
    #pragma unroll
    for (int mi = 0; mi < 4; ++mi) {
        float Mm = M[mi], Ss = S[mi];
        #pragma unroll
        for (int d = 16; d < 64; d <<= 1) {
            const float Mo = __shfl_xor(Mm, d), So = __shfl_xor(Ss, d);
            const float Mn = fmaxf(Mm, Mo);
            Ss = Ss * __builtin_amdgcn_exp2f(Mm - Mn) + So * __builtin_amdgcn_exp2f(Mo - Mn);
            Mm = Mn;
        }
        if (lg == 0)
            partials[slice * B_ROWS + mb + mi * 16 + lc] = Mm + __builtin_amdgcn_logf(Ss);
    }

    // ---- ticket: last FIN_BLOCKS finishers run the finalize ----
    __threadfence();
    if (tid == 0) s_ticket = atomicAdd(&ctrl[0], 1);
    __syncthreads();
    const int ticket = s_ticket;
    if (ticket < NEG_BLOCKS - FIN_BLOCKS) return;

    if (tid == 0) {
        while (__hip_atomic_load(&ctrl[0], __ATOMIC_ACQUIRE, __HIP_MEMORY_SCOPE_AGENT)
               < NEG_BLOCKS)
            __builtin_amdgcn_s_sleep(8);
    }
    __syncthreads();

    const int r = (ticket - (NEG_BLOCKS - FIN_BLOCKS)) * 256 + tid;
    float local = 0.f; int cnt = 0;
    const float lp2 = lse2_p[r];
    if (lp2 > -1e29f) {
        float p[NSLICE], mx = -1e30f;
        #pragma unroll
        for (int s = 0; s < NSLICE; ++s) {
            p[s] = __hip_atomic_load(&partials[s * B_ROWS + r],
                                     __ATOMIC_RELAXED, __HIP_MEMORY_SCOPE_AGENT);
            mx = fmaxf(mx, p[s]);
        }
        float Sa = 0.f;
        #pragma unroll
        for (int s = 0; s < NSLICE; ++s) Sa += __builtin_amdgcn_exp2f(p[s] - mx);
        const float lse2_all = mx + __builtin_amdgcn_logf(Sa);
        const float d = lse2_same[r] - lse2_all;
        const float corr = __builtin_amdgcn_logf(fmaxf(1.f - __builtin_amdgcn_exp2f(d), 1e-30f));
        const float z = LN2F * (lp2 + lse2_all + corr);
        local = fmaxf(z, 0.f) + log1pf(expf(-fabsf(z)));  // stable softplus
        cnt = 1;
    }
    #pragma unroll
    for (int d = 1; d < 64; d <<= 1) { local += __shfl_xor(local, d); cnt += __shfl_xor(cnt, d); }
    if (ln == 0) { wsum[wv] = local; wcnt[wv] = cnt; }
    __syncthreads();
    if (tid == 0) {
        const float ts = wsum[0] + wsum[1] + wsum[2] + wsum[3];
        const int tc = wcnt[0] + wcnt[1] + wcnt[2] + wcnt[3];
        atomicAdd((float*)&ctrl[2], ts);
        atomicAdd(&ctrl[3], tc);
        __threadfence();
        const int t2 = atomicAdd(&ctrl[1], 1);
        if (t2 == FIN_BLOCKS - 1) {
            __threadfence();
            const float gs = atomicAdd((float*)&ctrl[2], 0.0f);
            const int gc = atomicAdd(&ctrl[3], 0);
            out[0] = gs / (float)(gc > 1 ? gc : 1);
        }
    }
}

// ---------------- launch ----------------------------------------------------
extern "C" void kernel_launch(void* const* d_in, const int* in_sizes, int n_in,
                              void* d_out, int out_size, void* d_ws, size_t ws_size,
                              hipStream_t stream) {
    const float* feat = (const float*)d_in[0];
    const int* label = (const int*)d_in[1];
    float* out = (float*)d_out;
    char* ws = (char*)d_ws;

    unsigned int* fbp = (unsigned int*)(ws);                  // 2 MB packed bf16
    float* partials   = (float*)(ws + (2u << 20));            // 32*8192*4 = 1 MB
    float* lse2_p     = (float*)(ws + (3u << 20));            // 32 KB
    float* lse2_same  = (float*)(ws + (3u << 20) + 32768);    // 32 KB
    int*   ctrl       = (int*)  (ws + (3u << 20) + 65536);    // 16 B

    prep_k<<<2048 + NCLS, 256, 0, stream>>>(feat, label, fbp, lse2_p, lse2_same, ctrl);
    neg_k<<<NEG_BLOCKS, 256, 0, stream>>>((const unsigned short*)fbp, lse2_p, lse2_same,
                                          partials, ctrl, out);
}

// Round 6
// 136.577 us; speedup vs baseline: 1.4898x; 1.4898x over previous
//
#include <hip/hip_runtime.h>
#include <hip/hip_bf16.h>

typedef short bf16x8 __attribute__((ext_vector_type(8)));
typedef float f32x4 __attribute__((ext_vector_type(4)));

#define B_ROWS 8192
#define DIM 128
#define NCLS 512
#define MMAX 64
#define NSLICE 32
#define NEG_BLOCKS 1024

// gamma * log2(e): logits computed in base-2 throughout
#define G2 369.32993f
#define LN2F 0.69314718056f

// ============ K1: prep =====================================================
// blocks [0,2048): normalize 4 rows each -> PACKED bf16 fragment layout
//   frag16 F(T,k,lg,lc) = (T*4+k)*64 + lg*16 + lc holds row T*16+lc,
//   chunk lg+4k  -> neg_k fragment loads are contiguous 1KB per instruction.
// blocks [2048,2560): class c = bid-2048, self-contained positives.
__global__ __launch_bounds__(256) void prep_k(const float* __restrict__ feat,
                                              const int* __restrict__ label,
                                              unsigned int* __restrict__ fbp,
                                              float* __restrict__ lse2_p,
                                              float* __restrict__ lse2_same,
                                              int* __restrict__ ctrl) {
    const int bid = blockIdx.x;
    const int tid = threadIdx.x;
    const int wv = tid >> 6, ln = tid & 63;

    if (bid < 2048) {
        if (bid == 0 && tid < 4) ctrl[tid] = 0;  // done, gsum, gcnt, spare
        const int row = bid * 4 + wv;
        const float2 v = ((const float2*)feat)[row * 64 + ln];
        float ss = v.x * v.x + v.y * v.y;
        #pragma unroll
        for (int d = 1; d < 64; d <<= 1) ss += __shfl_xor(ss, d);
        const float inv = 1.0f / fmaxf(sqrtf(ss), 1e-12f);
        const float x = v.x * inv, y = v.y * inv;
        __hip_bfloat16 hx = __float2bfloat16(x), hy = __float2bfloat16(y);
        const unsigned int ux = *(const unsigned short*)&hx;
        const unsigned int uy = *(const unsigned short*)&hy;
        // lane ln holds row dword ln -> chunk c=ln>>2, dword-in-chunk j=ln&3
        const int T = row >> 4, lc = row & 15, c = ln >> 2, j = ln & 3;
        const int frag16 = (T * 4 + (c >> 2)) * 64 + (c & 3) * 16 + lc;
        fbp[frag16 * 4 + j] = ux | (uy << 16);
        return;
    }

    // ---- positives: class c, ballot-scan members, fp32-exact ----
    const int c = bid - 2048;
    __shared__ int rl[MMAX];
    __shared__ int s_total;
    __shared__ float F[MMAX][DIM + 1];

    if (wv == 0) {
        int base = 0;
        for (int it = 0; it < 32; ++it) {
            const int4 L = ((const int4*)label)[it * 64 + ln];
            const int lv[4] = {L.x, L.y, L.z, L.w};
            #pragma unroll
            for (int j = 0; j < 4; ++j) {
                const bool hit = (lv[j] == c);
                const unsigned long long mask = __ballot(hit);
                const int below = __popcll(mask & ((1ull << ln) - 1ull));
                const int slot = base + below;
                if (hit && slot < MMAX) rl[slot] = (it * 64 + ln) * 4 + j;
                base += __popcll(mask);
            }
        }
        if (ln == 0) s_total = base;
    }
    __syncthreads();
    const int total = s_total;
    const int m = total < MMAX ? total : MMAX;
    if (m == 0) return;
    const bool row_valid = (total >= 2);

    for (int i = wv; i < m; i += 4) {
        const int r = rl[i];
        const float2 v = ((const float2*)feat)[r * 64 + ln];
        float ss = v.x * v.x + v.y * v.y;
        #pragma unroll
        for (int d = 1; d < 64; d <<= 1) ss += __shfl_xor(ss, d);
        const float inv = 1.0f / fmaxf(sqrtf(ss), 1e-12f);
        F[i][2 * ln] = v.x * inv;
        F[i][2 * ln + 1] = v.y * inv;
    }
    __syncthreads();

    for (int i = wv; i < m; i += 4) {
        float s = 0.f;
        if (ln < m) {
            #pragma unroll 8
            for (int k = 0; k < DIM; ++k) s = fmaf(F[i][k], F[ln][k], s);
        }
        const bool act = (ln < m) && (ln != i);
        const float up = 1.25f - s;
        const float lp = act ? G2 * fmaxf(up, 0.f) * (up - 0.5f) : -1e30f;
        const float un = s + 0.25f;
        const float lnn = act ? G2 * fmaxf(un, 0.f) * (un - 0.5f) : -1e30f;
        float Mp = lp, Mn = lnn;
        #pragma unroll
        for (int d = 1; d < 64; d <<= 1) {
            Mp = fmaxf(Mp, __shfl_xor(Mp, d));
            Mn = fmaxf(Mn, __shfl_xor(Mn, d));
        }
        float Sp = act ? __builtin_amdgcn_exp2f(lp - Mp) : 0.f;
        float Sn = act ? __builtin_amdgcn_exp2f(lnn - Mn) : 0.f;
        #pragma unroll
        for (int d = 1; d < 64; d <<= 1) { Sp += __shfl_xor(Sp, d); Sn += __shfl_xor(Sn, d); }
        if (ln == 0) {
            const int row = rl[i];
            lse2_p[row]    = row_valid ? (Mp + __builtin_amdgcn_logf(Sp)) : -1e30f;
            lse2_same[row] = row_valid ? (Mn + __builtin_amdgcn_logf(Sn)) : -1e30f;
        }
    }
}

// ---------------- epilogue for one f32x4 acc --------------------------------
__device__ __forceinline__ void epi4(f32x4 acc, float& M, float& S,
                                     bool diag, int lc, int lg) {
    float u0 = acc[0] + 0.25f; float w0 = fmaf(G2, acc[0], -0.25f * G2);
    float u1 = acc[1] + 0.25f; float w1 = fmaf(G2, acc[1], -0.25f * G2);
    float u2 = acc[2] + 0.25f; float w2 = fmaf(G2, acc[2], -0.25f * G2);
    float u3 = acc[3] + 0.25f; float w3 = fmaf(G2, acc[3], -0.25f * G2);
    float l0 = fmaxf(u0, 0.f) * w0, l1 = fmaxf(u1, 0.f) * w1;
    float l2 = fmaxf(u2, 0.f) * w2, l3 = fmaxf(u3, 0.f) * w3;
    if (diag) {  // wave-uniform: the one diagonal tile
        const int base = lg * 4;
        l0 = (base + 0 == lc) ? -3.0e8f : l0;
        l1 = (base + 1 == lc) ? -3.0e8f : l1;
        l2 = (base + 2 == lc) ? -3.0e8f : l2;
        l3 = (base + 3 == lc) ? -3.0e8f : l3;
    }
    const float gm = fmaxf(fmaxf(l0, l1), fmaxf(l2, l3));
    // skip tiles that can't contribute > 2^-25 relative (wave-coherent)
    if (__any(gm > M - 25.f)) {
        const float Mn = fmaxf(M, gm);
        const float r  = __builtin_amdgcn_exp2f(M - Mn);
        const float e0 = __builtin_amdgcn_exp2f(l0 - Mn);
        const float e1 = __builtin_amdgcn_exp2f(l1 - Mn);
        const float e2 = __builtin_amdgcn_exp2f(l2 - Mn);
        const float e3 = __builtin_amdgcn_exp2f(l3 - Mn);
        S = fmaf(S, r, e0) + e1 + e2 + e3;
        M = Mn;
    }
}

// ============ K2: neg GEMM-LSE (no fences, no LDS) ==========================
__global__ __launch_bounds__(256, 4) void neg_k(const unsigned short* __restrict__ fb_,
                                                float* __restrict__ partials) {
    const int bid = blockIdx.x;
    const int tid = threadIdx.x;
    const int wv = tid >> 6, ln = tid & 63;
    const int lc = ln & 15, lg = ln >> 4;
    const int slice = bid & 31, mblk = bid >> 5;
    const int mb = mblk * 256 + wv * 64;
    const int mbT = mb >> 4;
    const bf16x8* pk = (const bf16x8*)fb_;

    bf16x8 a[4][4];
    #pragma unroll
    for (int mi = 0; mi < 4; ++mi)
        #pragma unroll
        for (int k = 0; k < 4; ++k)
            a[mi][k] = pk[((mbT + mi) * 4 + k) * 64 + ln];

    float M[4], S[4];
    #pragma unroll
    for (int mi = 0; mi < 4; ++mi) { M[mi] = -1e30f; S[mi] = 0.f; }

    const int nT0 = slice * 16;
    bf16x8 bA[4], bB[4];

    #define LOADB(dst, nT) { \
        _Pragma("unroll") \
        for (int k = 0; k < 4; ++k) dst[k] = pk[((nT) * 4 + k) * 64 + ln]; }

    #define STEP(bR, nT) { \
        f32x4 acc[4]; \
        _Pragma("unroll") \
        for (int mi = 0; mi < 4; ++mi) acc[mi] = (f32x4){0.f, 0.f, 0.f, 0.f}; \
        _Pragma("unroll") \
        for (int k = 0; k < 4; ++k) { \
            _Pragma("unroll") \
            for (int mi = 0; mi < 4; ++mi) \
                acc[mi] = __builtin_amdgcn_mfma_f32_16x16x32_bf16(bR[k], a[mi][k], acc[mi], 0, 0, 0); \
        } \
        _Pragma("unroll") \
        for (int mi = 0; mi < 4; ++mi) \
            epi4(acc[mi], M[mi], S[mi], (nT) * 16 == mb + mi * 16, lc, lg); }

    LOADB(bA, nT0);
    #pragma unroll 1
    for (int t = 0; t < 16; t += 2) {
        LOADB(bB, nT0 + t + 1);
        STEP(bA, nT0 + t);
        if (t + 2 < 16) LOADB(bA, nT0 + t + 2);
        STEP(bB, nT0 + t + 1);
    }
    #undef LOADB
    #undef STEP

    // merge lane groups (lanes l, l^16, l^32, l^48 hold disjoint n-subsets)
    #pragma unroll
    for (int mi = 0; mi < 4; ++mi) {
        float Mm = M[mi], Ss = S[mi];
        #pragma unroll
        for (int d = 16; d < 64; d <<= 1) {
            const float Mo = __shfl_xor(Mm, d), So = __shfl_xor(Ss, d);
            const float Mn = fmaxf(Mm, Mo);
            Ss = Ss * __builtin_amdgcn_exp2f(Mm - Mn) + So * __builtin_amdgcn_exp2f(Mo - Mn);
            Mm = Mn;
        }
        if (lg == 0)
            partials[slice * B_ROWS + mb + mi * 16 + lc] = Mm + __builtin_amdgcn_logf(Ss);
    }
}

// ============ K3: finalize (32 blocks; internal ticket writes out) ==========
__global__ __launch_bounds__(256) void finalize_k(const float* __restrict__ partials,
                                                  const float* __restrict__ lse2_p,
                                                  const float* __restrict__ lse2_same,
                                                  int* __restrict__ ctrl,
                                                  float* __restrict__ out) {
    const int r = blockIdx.x * 256 + threadIdx.x;
    float local = 0.f; int c = 0;
    const float lp2 = lse2_p[r];
    if (lp2 > -1e29f) {
        float p[NSLICE], mx = -1e30f;
        #pragma unroll
        for (int s = 0; s < NSLICE; ++s) { p[s] = partials[s * B_ROWS + r]; mx = fmaxf(mx, p[s]); }
        float Sa = 0.f;
        #pragma unroll
        for (int s = 0; s < NSLICE; ++s) Sa += __builtin_amdgcn_exp2f(p[s] - mx);
        const float lse2_all = mx + __builtin_amdgcn_logf(Sa);
        const float d = lse2_same[r] - lse2_all;
        const float corr = __builtin_amdgcn_logf(fmaxf(1.f - __builtin_amdgcn_exp2f(d), 1e-30f));
        const float z = LN2F * (lp2 + lse2_all + corr);
        local = fmaxf(z, 0.f) + log1pf(expf(-fabsf(z)));  // stable softplus
        c = 1;
    }
    #pragma unroll
    for (int d = 1; d < 64; d <<= 1) { local += __shfl_xor(local, d); c += __shfl_xor(c, d); }
    __shared__ float wsum[4];
    __shared__ int wcnt[4];
    const int wv = threadIdx.x >> 6;
    if ((threadIdx.x & 63) == 0) { wsum[wv] = local; wcnt[wv] = c; }
    __syncthreads();
    if (threadIdx.x == 0) {
        const float ts = wsum[0] + wsum[1] + wsum[2] + wsum[3];
        const int tc = wcnt[0] + wcnt[1] + wcnt[2] + wcnt[3];
        atomicAdd((float*)&ctrl[1], ts);
        atomicAdd(&ctrl[2], tc);
        __threadfence();
        const int ticket = atomicAdd(&ctrl[0], 1);
        if (ticket == (int)gridDim.x - 1) {
            const float gs = atomicAdd((float*)&ctrl[1], 0.0f);
            const int gc = atomicAdd(&ctrl[2], 0);
            out[0] = gs / (float)(gc > 1 ? gc : 1);
        }
    }
}

// ---------------- launch ----------------------------------------------------
extern "C" void kernel_launch(void* const* d_in, const int* in_sizes, int n_in,
                              void* d_out, int out_size, void* d_ws, size_t ws_size,
                              hipStream_t stream) {
    const float* feat = (const float*)d_in[0];
    const int* label = (const int*)d_in[1];
    float* out = (float*)d_out;
    char* ws = (char*)d_ws;

    unsigned int* fbp = (unsigned int*)(ws);                  // 2 MB packed bf16
    float* partials   = (float*)(ws + (2u << 20));            // 32*8192*4 = 1 MB
    float* lse2_p     = (float*)(ws + (3u << 20));            // 32 KB
    float* lse2_same  = (float*)(ws + (3u << 20) + 32768);    // 32 KB
    int*   ctrl       = (int*)  (ws + (3u << 20) + 65536);    // 16 B

    prep_k<<<2048 + NCLS, 256, 0, stream>>>(feat, label, fbp, lse2_p, lse2_same, ctrl);
    neg_k<<<NEG_BLOCKS, 256, 0, stream>>>((const unsigned short*)fbp, partials);
    finalize_k<<<NSLICE, 256, 0, stream>>>(partials, lse2_p, lse2_same, ctrl, out);
}

// Round 7
// 110.117 us; speedup vs baseline: 1.8478x; 1.2403x over previous
//
#include <hip/hip_runtime.h>
#include <hip/hip_bf16.h>

typedef short bf16x8 __attribute__((ext_vector_type(8)));
typedef float f32x4 __attribute__((ext_vector_type(4)));

#define B_ROWS 8192
#define DIM 128
#define NCLS 512
#define MMAX 64
#define NSLICE 32
#define NEG_BLOCKS 1024

// gamma * log2(e): logits computed in base-2 throughout
#define G2 369.32993f
#define G2D16 23.083121f
#define LN2F 0.69314718056f

// ============ K1: prep (LDS-free) ==========================================
// 512 blocks, block T normalizes rows [16T,16T+16) and stores PACKED bf16:
// thread t: row = 16T + (t>>4), elems q*8..q*8+8 (q=t&15); packed dword for
// elem-pair k2=(q*4+j) goes to g=(T*4+(q>>2))*256+(q&3)*64+(t>>4)*4+j -> one
// contiguous uint4 store per thread (verified identical to prior fbp layout).
__global__ __launch_bounds__(256) void prep_k(const float* __restrict__ feat,
                                              unsigned int* __restrict__ fbp,
                                              int* __restrict__ ctrl) {
    const int T = blockIdx.x;
    const int t = threadIdx.x;
    if (T == 0 && t < 4) ctrl[t] = 0;  // ticket, gsum, gcnt, spare
    const int rr = t >> 4, q = t & 15;
    const int row = T * 16 + rr;
    const float4* f4 = (const float4*)(feat + row * DIM + q * 8);
    const float4 v0 = f4[0], v1 = f4[1];
    float ss = v0.x * v0.x + v0.y * v0.y + v0.z * v0.z + v0.w * v0.w
             + v1.x * v1.x + v1.y * v1.y + v1.z * v1.z + v1.w * v1.w;
    #pragma unroll
    for (int d = 1; d < 16; d <<= 1) ss += __shfl_xor(ss, d);  // 16-lane row group
    const float inv = 1.0f / fmaxf(sqrtf(ss), 1e-12f);
    const float e[8] = {v0.x, v0.y, v0.z, v0.w, v1.x, v1.y, v1.z, v1.w};
    unsigned int w[4];
    #pragma unroll
    for (int j = 0; j < 4; ++j) {
        __hip_bfloat16 lo = __float2bfloat16(e[2 * j] * inv);
        __hip_bfloat16 hi = __float2bfloat16(e[2 * j + 1] * inv);
        w[j] = (unsigned int)*(unsigned short*)&lo |
               ((unsigned int)*(unsigned short*)&hi << 16);
    }
    const int g = (T * 4 + (q >> 2)) * 256 + (q & 3) * 64 + rr * 4;
    *(uint4*)(fbp + g) = make_uint4(w[0], w[1], w[2], w[3]);
}

// ---------------- epilogue for one f32x4 acc --------------------------------
// l = G2*relu(s+1/4)*(s-1/4) == G2*(max(s,-1/4)^2 - 1/16)  (3 VALU/elem)
__device__ __forceinline__ void epi4(f32x4 acc, float& M, float& S,
                                     bool diag, int lc, int lg) {
    const float t0 = fmaxf(acc[0], -0.25f), t1 = fmaxf(acc[1], -0.25f);
    const float t2 = fmaxf(acc[2], -0.25f), t3 = fmaxf(acc[3], -0.25f);
    float l0 = fmaf(t0 * t0, G2, -G2D16);
    float l1 = fmaf(t1 * t1, G2, -G2D16);
    float l2 = fmaf(t2 * t2, G2, -G2D16);
    float l3 = fmaf(t3 * t3, G2, -G2D16);
    if (diag) {  // wave-uniform: the one diagonal tile
        const int base = lg * 4;
        l0 = (base + 0 == lc) ? -3.0e8f : l0;
        l1 = (base + 1 == lc) ? -3.0e8f : l1;
        l2 = (base + 2 == lc) ? -3.0e8f : l2;
        l3 = (base + 3 == lc) ? -3.0e8f : l3;
    }
    const float gm = fmaxf(fmaxf(l0, l1), fmaxf(l2, l3));
    // skip tiles that can't contribute > 2^-25 relative (wave-coherent)
    if (__any(gm > M - 25.f)) {
        const float Mn = fmaxf(M, gm);
        const float r  = __builtin_amdgcn_exp2f(M - Mn);
        const float e0 = __builtin_amdgcn_exp2f(l0 - Mn);
        const float e1 = __builtin_amdgcn_exp2f(l1 - Mn);
        const float e2 = __builtin_amdgcn_exp2f(l2 - Mn);
        const float e3 = __builtin_amdgcn_exp2f(l3 - Mn);
        S = fmaf(S, r, e0) + e1 + e2 + e3;
        M = Mn;
    }
}

// ============ K2: mega = neg GEMM-LSE (bid<1024) + positives (bid>=1024) ====
__global__ __launch_bounds__(256, 4) void mega_k(const unsigned short* __restrict__ fb_,
                                                 const int* __restrict__ label,
                                                 float* __restrict__ partials,
                                                 float* __restrict__ lse2_p,
                                                 float* __restrict__ lse2_same) {
    __shared__ unsigned int F[MMAX][MMAX + 1];  // bf16x2-packed member rows
    __shared__ int rlw[4][MMAX];
    __shared__ int rl[MMAX];
    __shared__ int cntw[4];

    const int bid = blockIdx.x;
    const int tid = threadIdx.x;
    const int wv = tid >> 6, ln = tid & 63;

    if (bid < NEG_BLOCKS) {
        // ---- negative stream: 4x1 blocking, no LDS use, no fences ----
        const int lc = ln & 15, lg = ln >> 4;
        const int slice = bid & 31, mblk = bid >> 5;
        const int mb = mblk * 256 + wv * 64;
        const int mbT = mb >> 4;
        const bf16x8* pk = (const bf16x8*)fb_;

        bf16x8 a[4][4];
        #pragma unroll
        for (int mi = 0; mi < 4; ++mi)
            #pragma unroll
            for (int k = 0; k < 4; ++k)
                a[mi][k] = pk[((mbT + mi) * 4 + k) * 64 + ln];

        float M[4], S[4];
        #pragma unroll
        for (int mi = 0; mi < 4; ++mi) { M[mi] = -1e30f; S[mi] = 0.f; }

        const int nT0 = slice * 16;
        bf16x8 bA[4], bB[4];

        #define LOADB(dst, nT) { \
            _Pragma("unroll") \
            for (int k = 0; k < 4; ++k) dst[k] = pk[((nT) * 4 + k) * 64 + ln]; }

        #define STEP(bR, nT) { \
            f32x4 acc[4]; \
            _Pragma("unroll") \
            for (int mi = 0; mi < 4; ++mi) acc[mi] = (f32x4){0.f, 0.f, 0.f, 0.f}; \
            _Pragma("unroll") \
            for (int k = 0; k < 4; ++k) { \
                _Pragma("unroll") \
                for (int mi = 0; mi < 4; ++mi) \
                    acc[mi] = __builtin_amdgcn_mfma_f32_16x16x32_bf16(bR[k], a[mi][k], acc[mi], 0, 0, 0); \
            } \
            _Pragma("unroll") \
            for (int mi = 0; mi < 4; ++mi) \
                epi4(acc[mi], M[mi], S[mi], (nT) * 16 == mb + mi * 16, lc, lg); }

        LOADB(bA, nT0);
        #pragma unroll 1
        for (int t = 0; t < 16; t += 2) {
            LOADB(bB, nT0 + t + 1);
            STEP(bA, nT0 + t);
            if (t + 2 < 16) LOADB(bA, nT0 + t + 2);
            STEP(bB, nT0 + t + 1);
        }
        #undef LOADB
        #undef STEP

        #pragma unroll
        for (int mi = 0; mi < 4; ++mi) {
            float Mm = M[mi], Ss = S[mi];
            #pragma unroll
            for (int d = 16; d < 64; d <<= 1) {
                const float Mo = __shfl_xor(Mm, d), So = __shfl_xor(Ss, d);
                const float Mn = fmaxf(Mm, Mo);
                Ss = Ss * __builtin_amdgcn_exp2f(Mm - Mn) + So * __builtin_amdgcn_exp2f(Mo - Mn);
                Mm = Mn;
            }
            if (lg == 0)
                partials[slice * B_ROWS + mb + mi * 16 + lc] = Mm + __builtin_amdgcn_logf(Ss);
        }
        return;
    }

    // ---- positives: class c; 4-wave-parallel ballot scan ----
    const int c = bid - NEG_BLOCKS;
    {
        int cnt = 0;
        #pragma unroll 1
        for (int it = 0; it < 8; ++it) {
            const int4 L = ((const int4*)label)[wv * 512 + it * 64 + ln];
            const int lv[4] = {L.x, L.y, L.z, L.w};
            #pragma unroll
            for (int j = 0; j < 4; ++j) {
                const bool hit = (lv[j] == c);
                const unsigned long long mask = __ballot(hit);
                const int below = __popcll(mask & ((1ull << ln) - 1ull));
                const int slot = cnt + below;
                if (hit && slot < MMAX) rlw[wv][slot] = wv * 2048 + it * 256 + ln * 4 + j;
                cnt += __popcll(mask);
            }
        }
        if (ln == 0) cntw[wv] = cnt;
    }
    __syncthreads();
    const int c0 = cntw[0], c1 = cntw[1], c2 = cntw[2], c3 = cntw[3];
    const int total = c0 + c1 + c2 + c3;
    const int m = total < MMAX ? total : MMAX;
    if (m == 0) return;
    const bool row_valid = (total >= 2) && (total < B_ROWS);
    {
        const int offs = (wv > 0 ? c0 : 0) + (wv > 1 ? c1 : 0) + (wv > 2 ? c2 : 0);
        const int mycnt = cntw[wv] < MMAX ? cntw[wv] : MMAX;
        if (ln < mycnt) {
            const int slot = offs + ln;
            if (slot < m) rl[slot] = rlw[wv][ln];
        }
    }
    __syncthreads();

    // stage member rows (bf16x2-packed) from the packed fbp layout
    const unsigned int* fbp = (const unsigned int*)fb_;
    for (int i = wv; i < m; i += 4) {
        const int r = rl[i];
        const int g = ((r >> 4) * 4 + (ln >> 4)) * 256 + ((ln >> 2) & 3) * 64 +
                      (r & 15) * 4 + (ln & 3);
        F[i][ln] = fbp[g];
    }
    __syncthreads();

    for (int i = wv; i < m; i += 4) {
        float s = 0.f;
        if (ln < m) {
            #pragma unroll 8
            for (int k = 0; k < 64; ++k) {
                const unsigned int wi = F[i][k], wj = F[ln][k];
                const float li = __uint_as_float(wi << 16);
                const float hi = __uint_as_float(wi & 0xffff0000u);
                const float lj = __uint_as_float(wj << 16);
                const float hj = __uint_as_float(wj & 0xffff0000u);
                s = fmaf(li, lj, s);
                s = fmaf(hi, hj, s);
            }
        }
        const bool act = (ln < m) && (ln != i);
        const float up = 1.25f - s;
        const float lp = act ? G2 * fmaxf(up, 0.f) * (up - 0.5f) : -1e30f;
        const float un = s + 0.25f;
        const float lnn = act ? G2 * fmaxf(un, 0.f) * (un - 0.5f) : -1e30f;
        float Mp = lp, Mn = lnn;
        #pragma unroll
        for (int d = 1; d < 64; d <<= 1) {
            Mp = fmaxf(Mp, __shfl_xor(Mp, d));
            Mn = fmaxf(Mn, __shfl_xor(Mn, d));
        }
        float Sp = act ? __builtin_amdgcn_exp2f(lp - Mp) : 0.f;
        float Sn = act ? __builtin_amdgcn_exp2f(lnn - Mn) : 0.f;
        #pragma unroll
        for (int d = 1; d < 64; d <<= 1) { Sp += __shfl_xor(Sp, d); Sn += __shfl_xor(Sn, d); }
        if (ln == 0) {
            const int row = rl[i];
            lse2_p[row]    = row_valid ? (Mp + __builtin_amdgcn_logf(Sp)) : -1e30f;
            lse2_same[row] = row_valid ? (Mn + __builtin_amdgcn_logf(Sn)) : -1e30f;
        }
    }
}

// ============ K3: finalize (32 blocks; internal ticket writes out) ==========
__global__ __launch_bounds__(256) void finalize_k(const float* __restrict__ partials,
                                                  const float* __restrict__ lse2_p,
                                                  const float* __restrict__ lse2_same,
                                                  int* __restrict__ ctrl,
                                                  float* __restrict__ out) {
    const int r = blockIdx.x * 256 + threadIdx.x;
    float local = 0.f; int c = 0;
    const float lp2 = lse2_p[r];
    if (lp2 > -1e29f) {
        float p[NSLICE], mx = -1e30f;
        #pragma unroll
        for (int s = 0; s < NSLICE; ++s) { p[s] = partials[s * B_ROWS + r]; mx = fmaxf(mx, p[s]); }
        float Sa = 0.f;
        #pragma unroll
        for (int s = 0; s < NSLICE; ++s) Sa += __builtin_amdgcn_exp2f(p[s] - mx);
        const float lse2_all = mx + __builtin_amdgcn_logf(Sa);
        const float d = lse2_same[r] - lse2_all;
        const float corr = __builtin_amdgcn_logf(fmaxf(1.f - __builtin_amdgcn_exp2f(d), 1e-30f));
        const float z = LN2F * (lp2 + lse2_all + corr);
        local = fmaxf(z, 0.f) + log1pf(expf(-fabsf(z)));  // stable softplus
        c = 1;
    }
    #pragma unroll
    for (int d = 1; d < 64; d <<= 1) { local += __shfl_xor(local, d); c += __shfl_xor(c, d); }
    __shared__ float wsum[4];
    __shared__ int wcnt[4];
    const int wv = threadIdx.x >> 6;
    if ((threadIdx.x & 63) == 0) { wsum[wv] = local; wcnt[wv] = c; }
    __syncthreads();
    if (threadIdx.x == 0) {
        const float ts = wsum[0] + wsum[1] + wsum[2] + wsum[3];
        const int tc = wcnt[0] + wcnt[1] + wcnt[2] + wcnt[3];
        atomicAdd((float*)&ctrl[1], ts);
        atomicAdd(&ctrl[2], tc);
        __threadfence();
        const int ticket = atomicAdd(&ctrl[0], 1);
        if (ticket == (int)gridDim.x - 1) {
            const float gs = atomicAdd((float*)&ctrl[1], 0.0f);
            const int gc = atomicAdd(&ctrl[2], 0);
            out[0] = gs / (float)(gc > 1 ? gc : 1);
        }
    }
}

// ---------------- launch ----------------------------------------------------
extern "C" void kernel_launch(void* const* d_in, const int* in_sizes, int n_in,
                              void* d_out, int out_size, void* d_ws, size_t ws_size,
                              hipStream_t stream) {
    const float* feat = (const float*)d_in[0];
    const int* label = (const int*)d_in[1];
    float* out = (float*)d_out;
    char* ws = (char*)d_ws;

    unsigned int* fbp = (unsigned int*)(ws);                  // 2 MB packed bf16
    float* partials   = (float*)(ws + (2u << 20));            // 32*8192*4 = 1 MB
    float* lse2_p     = (float*)(ws + (3u << 20));            // 32 KB
    float* lse2_same  = (float*)(ws + (3u << 20) + 32768);    // 32 KB
    int*   ctrl       = (int*)  (ws + (3u << 20) + 65536);    // 16 B

    prep_k<<<NCLS, 256, 0, stream>>>(feat, fbp, ctrl);
    mega_k<<<NEG_BLOCKS + NCLS, 256, 0, stream>>>((const unsigned short*)fbp, label,
                                                  partials, lse2_p, lse2_same);
    finalize_k<<<NSLICE, 256, 0, stream>>>(partials, lse2_p, lse2_same, ctrl, out);
}

// Round 8
// 100.272 us; speedup vs baseline: 2.0293x; 1.0982x over previous
//
#include <hip/hip_runtime.h>
#include <hip/hip_bf16.h>

typedef short bf16x8 __attribute__((ext_vector_type(8)));
typedef float f32x4 __attribute__((ext_vector_type(4)));

#define B_ROWS 8192
#define DIM 128
#define NCLS 512
#define MMAX 64
#define NSLICE 64
#define NPAIR 2080   // 64*65/2 pair-tiles of 128x128

// gamma * log2(e): logits computed in base-2 throughout
#define G2 369.32993f
#define G2D16 23.083121f
#define LN2F 0.69314718056f

// ============ K1: prep (LDS-free) ==========================================
// 512 blocks, block T normalizes rows [16T,16T+16) and stores PACKED bf16
// fragment layout: frag16 (T4,k,lg,lc) at (T4*4+k)*64+lg*16+lc holds row
// T4*16+lc chunk lg+4k (verified layout, unchanged since R4).
__global__ __launch_bounds__(256) void prep_k(const float* __restrict__ feat,
                                              unsigned int* __restrict__ fbp,
                                              int* __restrict__ ctrl) {
    const int T = blockIdx.x;
    const int t = threadIdx.x;
    if (T == 0 && t < 4) ctrl[t] = 0;  // ticket, gsum, gcnt, spare
    const int rr = t >> 4, q = t & 15;
    const int row = T * 16 + rr;
    const float4* f4 = (const float4*)(feat + row * DIM + q * 8);
    const float4 v0 = f4[0], v1 = f4[1];
    float ss = v0.x * v0.x + v0.y * v0.y + v0.z * v0.z + v0.w * v0.w
             + v1.x * v1.x + v1.y * v1.y + v1.z * v1.z + v1.w * v1.w;
    #pragma unroll
    for (int d = 1; d < 16; d <<= 1) ss += __shfl_xor(ss, d);  // 16-lane row group
    const float inv = 1.0f / fmaxf(sqrtf(ss), 1e-12f);
    const float e[8] = {v0.x, v0.y, v0.z, v0.w, v1.x, v1.y, v1.z, v1.w};
    unsigned int w[4];
    #pragma unroll
    for (int j = 0; j < 4; ++j) {
        __hip_bfloat16 lo = __float2bfloat16(e[2 * j] * inv);
        __hip_bfloat16 hi = __float2bfloat16(e[2 * j + 1] * inv);
        w[j] = (unsigned int)*(unsigned short*)&lo |
               ((unsigned int)*(unsigned short*)&hi << 16);
    }
    const int g = (T * 4 + (q >> 2)) * 256 + (q & 3) * 64 + rr * 4;
    *(uint4*)(fbp + g) = make_uint4(w[0], w[1], w[2], w[3]);
}

// l = G2*relu(s+1/4)*(s-1/4) == G2*(max(s,-1/4)^2 - 1/16); bounded >= -23.08,
// clamp <=120 so raw exp2 sums stay finite in fp32 (no running max needed).
#define ELEM(sv) __builtin_amdgcn_exp2f(fminf(fmaf(fmaxf((sv), -0.25f) * fmaxf((sv), -0.25f), G2, -G2D16), 120.f))

// ============ K2: mega = symmetric pair-tile neg-LSE + positives ============
// blocks [0,NPAIR): pair (I,J), I<=J, 128x128 sim tile computed ONCE.
//   row-side: rows of I reduced over J-cols -> PR[J][r], r in I
//   col-side: (I<J) cols reduced over I-rows via shfl -> PR[I][c], c in J
// blocks [NPAIR, NPAIR+512): per-class positives (fp32-on-bf16, unchanged).
__global__ __launch_bounds__(256, 4) void mega_k(const unsigned short* __restrict__ fb_,
                                                 const int* __restrict__ label,
                                                 float* __restrict__ PR,
                                                 float* __restrict__ lse2_p,
                                                 float* __restrict__ lse2_same) {
    __shared__ float colS[4][128];
    __shared__ unsigned int F[MMAX][MMAX + 1];  // bf16x2-packed member rows
    __shared__ int rlw[4][MMAX];
    __shared__ int rl[MMAX];
    __shared__ int cntw[4];

    const int bid = blockIdx.x;
    const int tid = threadIdx.x;
    const int wv = tid >> 6, ln = tid & 63;

    if (bid < NPAIR) {
        // ---- decode pair (I,J), I<=J ----
        int I = (int)((129.0f - sqrtf(16641.0f - 8.0f * (float)bid)) * 0.5f);
        while (I * 64 - I * (I - 1) / 2 > bid) --I;
        while ((I + 1) * 64 - (I + 1) * I / 2 <= bid) ++I;
        const int J = I + (bid - (I * 64 - I * (I - 1) / 2));
        const bool offd = (I != J);

        const int lc = ln & 15, lg = ln >> 4;
        const int wv2 = wv * 2;
        const bf16x8* pk = (const bf16x8*)fb_;

        // A fragments: wave's 32 I-rows (2 row-tiles of 16)
        const int Ta0 = I * 8 + wv2;
        bf16x8 a0[4], a1[4];
        #pragma unroll
        for (int k = 0; k < 4; ++k) {
            a0[k] = pk[(Ta0 * 4 + k) * 64 + ln];
            a1[k] = pk[((Ta0 + 1) * 4 + k) * 64 + ln];
        }

        float Sr0 = 0.f, Sr1 = 0.f;
        bf16x8 bA[4], bB[4];

        #define LOADB(dst, t) { \
            _Pragma("unroll") \
            for (int k = 0; k < 4; ++k) dst[k] = pk[((J * 8 + (t)) * 4 + k) * 64 + ln]; }

        #define STEP(bR, t) { \
            f32x4 acc0 = {0.f, 0.f, 0.f, 0.f}, acc1 = acc0; \
            _Pragma("unroll") \
            for (int k = 0; k < 4; ++k) { \
                acc0 = __builtin_amdgcn_mfma_f32_16x16x32_bf16(bR[k], a0[k], acc0, 0, 0, 0); \
                acc1 = __builtin_amdgcn_mfma_f32_16x16x32_bf16(bR[k], a1[k], acc1, 0, 0, 0); \
            } \
            float e00 = ELEM(acc0[0]), e01 = ELEM(acc0[1]); \
            float e02 = ELEM(acc0[2]), e03 = ELEM(acc0[3]); \
            float e10 = ELEM(acc1[0]), e11 = ELEM(acc1[1]); \
            float e12 = ELEM(acc1[2]), e13 = ELEM(acc1[3]); \
            if (!offd && (t) == wv2) {        /* diag sub-tile of acc0 */ \
                const int base = lg * 4; \
                e00 = (base + 0 == lc) ? 0.f : e00; \
                e01 = (base + 1 == lc) ? 0.f : e01; \
                e02 = (base + 2 == lc) ? 0.f : e02; \
                e03 = (base + 3 == lc) ? 0.f : e03; \
            } \
            if (!offd && (t) == wv2 + 1) {    /* diag sub-tile of acc1 */ \
                const int base = lg * 4; \
                e10 = (base + 0 == lc) ? 0.f : e10; \
                e11 = (base + 1 == lc) ? 0.f : e11; \
                e12 = (base + 2 == lc) ? 0.f : e12; \
                e13 = (base + 3 == lc) ? 0.f : e13; \
            } \
            Sr0 += (e00 + e01) + (e02 + e03); \
            Sr1 += (e10 + e11) + (e12 + e13); \
            if (offd) { \
                float c0 = e00 + e10, c1 = e01 + e11; \
                float c2 = e02 + e12, c3 = e03 + e13; \
                _Pragma("unroll") \
                for (int d = 1; d < 16; d <<= 1) { \
                    c0 += __shfl_xor(c0, d); c1 += __shfl_xor(c1, d); \
                    c2 += __shfl_xor(c2, d); c3 += __shfl_xor(c3, d); \
                } \
                if (lc == 0) \
                    *(float4*)&colS[wv][(t) * 16 + lg * 4] = make_float4(c0, c1, c2, c3); \
            } }

        LOADB(bA, 0);
        #pragma unroll 1
        for (int t = 0; t < 8; t += 2) {
            LOADB(bB, t + 1);
            STEP(bA, t);
            if (t + 2 < 8) LOADB(bA, t + 2);
            STEP(bB, t + 1);
        }
        #undef LOADB
        #undef STEP

        // row-side: merge lg groups (disjoint col subsets), write PR[J][r]
        #pragma unroll
        for (int d = 16; d < 64; d <<= 1) {
            Sr0 += __shfl_xor(Sr0, d);
            Sr1 += __shfl_xor(Sr1, d);
        }
        if (lg == 0) {
            const int r = I * 128 + wv * 32 + lc;
            PR[J * B_ROWS + r]      = __builtin_amdgcn_logf(Sr0);
            PR[J * B_ROWS + r + 16] = __builtin_amdgcn_logf(Sr1);
        }

        // col-side: merge the 4 waves' partial col sums, write PR[I][c]
        if (offd) {
            __syncthreads();
            if (tid < 128) {
                const float tot = colS[0][tid] + colS[1][tid] +
                                  colS[2][tid] + colS[3][tid];
                PR[I * B_ROWS + J * 128 + tid] = __builtin_amdgcn_logf(tot);
            }
        }
        return;
    }

    // ---- positives: class c; 4-wave-parallel ballot scan (unchanged) ----
    const int c = bid - NPAIR;
    {
        int cnt = 0;
        #pragma unroll 1
        for (int it = 0; it < 8; ++it) {
            const int4 L = ((const int4*)label)[wv * 512 + it * 64 + ln];
            const int lv[4] = {L.x, L.y, L.z, L.w};
            #pragma unroll
            for (int j = 0; j < 4; ++j) {
                const bool hit = (lv[j] == c);
                const unsigned long long mask = __ballot(hit);
                const int below = __popcll(mask & ((1ull << ln) - 1ull));
                const int slot = cnt + below;
                if (hit && slot < MMAX) rlw[wv][slot] = wv * 2048 + it * 256 + ln * 4 + j;
                cnt += __popcll(mask);
            }
        }
        if (ln == 0) cntw[wv] = cnt;
    }
    __syncthreads();
    const int c0 = cntw[0], c1 = cntw[1], c2 = cntw[2], c3 = cntw[3];
    const int total = c0 + c1 + c2 + c3;
    const int m = total < MMAX ? total : MMAX;
    if (m == 0) return;
    const bool row_valid = (total >= 2) && (total < B_ROWS);
    {
        const int offs = (wv > 0 ? c0 : 0) + (wv > 1 ? c1 : 0) + (wv > 2 ? c2 : 0);
        const int mycnt = cntw[wv] < MMAX ? cntw[wv] : MMAX;
        if (ln < mycnt) {
            const int slot = offs + ln;
            if (slot < m) rl[slot] = rlw[wv][ln];
        }
    }
    __syncthreads();

    const unsigned int* fbp = (const unsigned int*)fb_;
    for (int i = wv; i < m; i += 4) {
        const int r = rl[i];
        const int g = ((r >> 4) * 4 + (ln >> 4)) * 256 + ((ln >> 2) & 3) * 64 +
                      (r & 15) * 4 + (ln & 3);
        F[i][ln] = fbp[g];
    }
    __syncthreads();

    for (int i = wv; i < m; i += 4) {
        float s = 0.f;
        if (ln < m) {
            #pragma unroll 8
            for (int k = 0; k < 64; ++k) {
                const unsigned int wi = F[i][k], wj = F[ln][k];
                const float li = __uint_as_float(wi << 16);
                const float hi = __uint_as_float(wi & 0xffff0000u);
                const float lj = __uint_as_float(wj << 16);
                const float hj = __uint_as_float(wj & 0xffff0000u);
                s = fmaf(li, lj, s);
                s = fmaf(hi, hj, s);
            }
        }
        const bool act = (ln < m) && (ln != i);
        const float up = 1.25f - s;
        const float lp = act ? G2 * fmaxf(up, 0.f) * (up - 0.5f) : -1e30f;
        const float un = s + 0.25f;
        const float lnn = act ? G2 * fmaxf(un, 0.f) * (un - 0.5f) : -1e30f;
        float Mp = lp, Mn = lnn;
        #pragma unroll
        for (int d = 1; d < 64; d <<= 1) {
            Mp = fmaxf(Mp, __shfl_xor(Mp, d));
            Mn = fmaxf(Mn, __shfl_xor(Mn, d));
        }
        float Sp = act ? __builtin_amdgcn_exp2f(lp - Mp) : 0.f;
        float Sn = act ? __builtin_amdgcn_exp2f(lnn - Mn) : 0.f;
        #pragma unroll
        for (int d = 1; d < 64; d <<= 1) { Sp += __shfl_xor(Sp, d); Sn += __shfl_xor(Sn, d); }
        if (ln == 0) {
            const int row = rl[i];
            lse2_p[row]    = row_valid ? (Mp + __builtin_amdgcn_logf(Sp)) : -1e30f;
            lse2_same[row] = row_valid ? (Mn + __builtin_amdgcn_logf(Sn)) : -1e30f;
        }
    }
}

// ============ K3: finalize (32 blocks; internal ticket writes out) ==========
__global__ __launch_bounds__(256) void finalize_k(const float* __restrict__ PR,
                                                  const float* __restrict__ lse2_p,
                                                  const float* __restrict__ lse2_same,
                                                  int* __restrict__ ctrl,
                                                  float* __restrict__ out) {
    const int r = blockIdx.x * 256 + threadIdx.x;
    float local = 0.f; int c = 0;
    const float lp2 = lse2_p[r];
    if (lp2 > -1e29f) {
        float mx = -1e30f, Sa = 0.f;
        #pragma unroll 8
        for (int s = 0; s < NSLICE; ++s) {
            const float v = PR[s * B_ROWS + r];
            const float nm = fmaxf(mx, v);
            Sa = Sa * __builtin_amdgcn_exp2f(mx - nm) + __builtin_amdgcn_exp2f(v - nm);
            mx = nm;
        }
        const float lse2_all = mx + __builtin_amdgcn_logf(Sa);
        const float d = lse2_same[r] - lse2_all;
        const float corr = __builtin_amdgcn_logf(fmaxf(1.f - __builtin_amdgcn_exp2f(d), 1e-30f));
        const float z = LN2F * (lp2 + lse2_all + corr);
        local = fmaxf(z, 0.f) + log1pf(expf(-fabsf(z)));  // stable softplus
        c = 1;
    }
    #pragma unroll
    for (int d = 1; d < 64; d <<= 1) { local += __shfl_xor(local, d); c += __shfl_xor(c, d); }
    __shared__ float wsum[4];
    __shared__ int wcnt[4];
    const int wv = threadIdx.x >> 6;
    if ((threadIdx.x & 63) == 0) { wsum[wv] = local; wcnt[wv] = c; }
    __syncthreads();
    if (threadIdx.x == 0) {
        const float ts = wsum[0] + wsum[1] + wsum[2] + wsum[3];
        const int tc = wcnt[0] + wcnt[1] + wcnt[2] + wcnt[3];
        atomicAdd((float*)&ctrl[1], ts);
        atomicAdd(&ctrl[2], tc);
        __threadfence();
        const int ticket = atomicAdd(&ctrl[0], 1);
        if (ticket == (int)gridDim.x - 1) {
            const float gs = atomicAdd((float*)&ctrl[1], 0.0f);
            const int gc = atomicAdd(&ctrl[2], 0);
            out[0] = gs / (float)(gc > 1 ? gc : 1);
        }
    }
}

// ---------------- launch ----------------------------------------------------
extern "C" void kernel_launch(void* const* d_in, const int* in_sizes, int n_in,
                              void* d_out, int out_size, void* d_ws, size_t ws_size,
                              hipStream_t stream) {
    const float* feat = (const float*)d_in[0];
    const int* label = (const int*)d_in[1];
    float* out = (float*)d_out;
    char* ws = (char*)d_ws;

    unsigned int* fbp = (unsigned int*)(ws);                  // 2 MB packed bf16
    float* PR         = (float*)(ws + (2u << 20));            // 64*8192*4 = 2 MB
    float* lse2_p     = (float*)(ws + (4u << 20));            // 32 KB
    float* lse2_same  = (float*)(ws + (4u << 20) + 32768);    // 32 KB
    int*   ctrl       = (int*)  (ws + (4u << 20) + 65536);    // 16 B

    prep_k<<<NCLS, 256, 0, stream>>>(feat, fbp, ctrl);
    mega_k<<<NPAIR + NCLS, 256, 0, stream>>>((const unsigned short*)fbp, label,
                                             PR, lse2_p, lse2_same);
    finalize_k<<<B_ROWS / 256, 256, 0, stream>>>(PR, lse2_p, lse2_same, ctrl, out);
}

// Round 10
// 99.706 us; speedup vs baseline: 2.0408x; 1.0057x over previous
//
#include <hip/hip_runtime.h>
#include <hip/hip_bf16.h>

typedef short bf16x8 __attribute__((ext_vector_type(8)));
typedef float f32x4 __attribute__((ext_vector_type(4)));

#define B_ROWS 8192
#define DIM 128
#define NCLS 512
#define MMAX 64
#define NSLICE 64
#define NPAIR 2080   // 64*65/2 pair-tiles of 128x128

// gamma * log2(e): logits computed in base-2 throughout
#define G2 369.32993f
// l - 64 bias folded into the constant: exp2(l-64); values in [2^-87, 2^56]
#define G2D16B 87.083121f
#define LN2F 0.69314718056f

// ============ K1: prep (LDS-free) ==========================================
// 512 blocks, block T normalizes rows [16T,16T+16) and stores PACKED bf16
// fragment layout: frag16 (T4,k,lg,lc) at (T4*4+k)*64+lg*16+lc holds row
// T4*16+lc chunk lg+4k (verified layout, unchanged since R4).
__global__ __launch_bounds__(256) void prep_k(const float* __restrict__ feat,
                                              unsigned int* __restrict__ fbp,
                                              int* __restrict__ ctrl) {
    const int T = blockIdx.x;
    const int t = threadIdx.x;
    if (T == 0 && t < 4) ctrl[t] = 0;  // ticket, gsum, gcnt, spare
    const int rr = t >> 4, q = t & 15;
    const int row = T * 16 + rr;
    const float4* f4 = (const float4*)(feat + row * DIM + q * 8);
    const float4 v0 = f4[0], v1 = f4[1];
    float ss = v0.x * v0.x + v0.y * v0.y + v0.z * v0.z + v0.w * v0.w
             + v1.x * v1.x + v1.y * v1.y + v1.z * v1.z + v1.w * v1.w;
    #pragma unroll
    for (int d = 1; d < 16; d <<= 1) ss += __shfl_xor(ss, d);  // 16-lane row group
    const float inv = 1.0f / fmaxf(sqrtf(ss), 1e-12f);
    const float e[8] = {v0.x, v0.y, v0.z, v0.w, v1.x, v1.y, v1.z, v1.w};
    unsigned int w[4];
    #pragma unroll
    for (int j = 0; j < 4; ++j) {
        __hip_bfloat16 lo = __float2bfloat16(e[2 * j] * inv);
        __hip_bfloat16 hi = __float2bfloat16(e[2 * j + 1] * inv);
        w[j] = (unsigned int)*(unsigned short*)&lo |
               ((unsigned int)*(unsigned short*)&hi << 16);
    }
    const int g = (T * 4 + (q >> 2)) * 256 + (q & 3) * 64 + rr * 4;
    *(uint4*)(fbp + g) = make_uint4(w[0], w[1], w[2], w[3]);
}

// e = exp2(l - 64), l = G2*(max(s,-1/4)^2 - 1/16) in [-23.08, clamp];
// clamp biased exponent at 56 so row sums stay finite in fp32.
#define ELEM(sv) __builtin_amdgcn_exp2f(fminf(fmaf(fmaxf((sv), -0.25f) * fmaxf((sv), -0.25f), G2, -G2D16B), 56.f))

// ============ K2: mega = symmetric pair-tile neg-sums + positives ===========
// blocks [0,NPAIR): pair (I,J), I<=J, 128x128 sim tile computed ONCE.
//   row-side: rows of I summed over J-cols -> PR[J][r] (RAW biased sums)
//   col-side: (I<J) cols summed over I-rows via shfl -> PR[I][c]
// blocks [NPAIR, NPAIR+512): per-class positives (fp32-on-bf16, log2 domain).
__global__ __launch_bounds__(256, 4) void mega_k(const unsigned short* __restrict__ fb_,
                                                 const int* __restrict__ label,
                                                 float* __restrict__ PR,
                                                 float* __restrict__ lse2_p,
                                                 float* __restrict__ lse2_same) {
    __shared__ float colS[4][128];
    __shared__ unsigned int F[MMAX][MMAX + 1];  // bf16x2-packed member rows
    __shared__ int rlw[4][MMAX];
    __shared__ int rl[MMAX];
    __shared__ int cntw[4];

    const int bid = blockIdx.x;
    const int tid = threadIdx.x;
    const int wv = tid >> 6, ln = tid & 63;

    if (bid < NPAIR) {
        // ---- decode pair (I,J), I<=J ----
        int I = (int)((129.0f - sqrtf(16641.0f - 8.0f * (float)bid)) * 0.5f);
        while (I * 64 - I * (I - 1) / 2 > bid) --I;
        while ((I + 1) * 64 - (I + 1) * I / 2 <= bid) ++I;
        const int J = I + (bid - (I * 64 - I * (I - 1) / 2));
        const bool offd = (I != J);

        const int lc = ln & 15, lg = ln >> 4;
        const int wv2 = wv * 2;
        const bf16x8* pk = (const bf16x8*)fb_;

        // A fragments: wave's 32 I-rows (2 row-tiles of 16)
        const int Ta0 = I * 8 + wv2;
        bf16x8 a0[4], a1[4];
        #pragma unroll
        for (int k = 0; k < 4; ++k) {
            a0[k] = pk[(Ta0 * 4 + k) * 64 + ln];
            a1[k] = pk[((Ta0 + 1) * 4 + k) * 64 + ln];
        }

        float Sr0 = 0.f, Sr1 = 0.f;
        bf16x8 bA[4], bB[4];
        // strength-reduced B base: index (J*8+t)*4*64 + k*64 + ln
        const bf16x8* pB = pk + J * 2048 + ln;

        #define LOADB(dst, base) { \
            _Pragma("unroll") \
            for (int k = 0; k < 4; ++k) dst[k] = (base)[k * 64]; }

        #define STEP(bR, t) { \
            f32x4 acc0 = {0.f, 0.f, 0.f, 0.f}, acc1 = acc0; \
            _Pragma("unroll") \
            for (int k = 0; k < 4; ++k) { \
                acc0 = __builtin_amdgcn_mfma_f32_16x16x32_bf16(bR[k], a0[k], acc0, 0, 0, 0); \
                acc1 = __builtin_amdgcn_mfma_f32_16x16x32_bf16(bR[k], a1[k], acc1, 0, 0, 0); \
            } \
            float e00 = ELEM(acc0[0]), e01 = ELEM(acc0[1]); \
            float e02 = ELEM(acc0[2]), e03 = ELEM(acc0[3]); \
            float e10 = ELEM(acc1[0]), e11 = ELEM(acc1[1]); \
            float e12 = ELEM(acc1[2]), e13 = ELEM(acc1[3]); \
            if (!offd && (t) == wv2) { \
                const int base = lg * 4; \
                e00 = (base + 0 == lc) ? 0.f : e00; \
                e01 = (base + 1 == lc) ? 0.f : e01; \
                e02 = (base + 2 == lc) ? 0.f : e02; \
                e03 = (base + 3 == lc) ? 0.f : e03; \
            } \
            if (!offd && (t) == wv2 + 1) { \
                const int base = lg * 4; \
                e10 = (base + 0 == lc) ? 0.f : e10; \
                e11 = (base + 1 == lc) ? 0.f : e11; \
                e12 = (base + 2 == lc) ? 0.f : e12; \
                e13 = (base + 3 == lc) ? 0.f : e13; \
            } \
            Sr0 += (e00 + e01) + (e02 + e03); \
            Sr1 += (e10 + e11) + (e12 + e13); \
            if (offd) { \
                float c0 = e00 + e10, c1 = e01 + e11; \
                float c2 = e02 + e12, c3 = e03 + e13; \
                _Pragma("unroll") \
                for (int d = 1; d < 16; d <<= 1) { \
                    c0 += __shfl_xor(c0, d); c1 += __shfl_xor(c1, d); \
                    c2 += __shfl_xor(c2, d); c3 += __shfl_xor(c3, d); \
                } \
                if (lc == 0) \
                    *(float4*)&colS[wv][(t) * 16 + lg * 4] = make_float4(c0, c1, c2, c3); \
            } }

        LOADB(bA, pB);
        #pragma unroll 1
        for (int t = 0; t < 8; t += 2) {
            LOADB(bB, pB + 256);
            STEP(bA, t);
            if (t + 2 < 8) LOADB(bA, pB + 512);
            STEP(bB, t + 1);
            pB += 512;
        }
        #undef LOADB
        #undef STEP

        // row-side: merge lg groups (disjoint col subsets), write RAW sums
        #pragma unroll
        for (int d = 16; d < 64; d <<= 1) {
            Sr0 += __shfl_xor(Sr0, d);
            Sr1 += __shfl_xor(Sr1, d);
        }
        if (lg == 0) {
            const int r = I * 128 + wv * 32 + lc;
            PR[J * B_ROWS + r]      = Sr0;
            PR[J * B_ROWS + r + 16] = Sr1;
        }

        // col-side: merge the 4 waves' partial col sums, write RAW sums
        if (offd) {
            __syncthreads();
            if (tid < 128) {
                const float tot = colS[0][tid] + colS[1][tid] +
                                  colS[2][tid] + colS[3][tid];
                PR[I * B_ROWS + J * 128 + tid] = tot;
            }
        }
        return;
    }

    // ---- positives: class c; 4-wave-parallel ballot scan (unchanged) ----
    const int c = bid - NPAIR;
    {
        int cnt = 0;
        #pragma unroll 1
        for (int it = 0; it < 8; ++it) {
            const int4 L = ((const int4*)label)[wv * 512 + it * 64 + ln];
            const int lv[4] = {L.x, L.y, L.z, L.w};
            #pragma unroll
            for (int j = 0; j < 4; ++j) {
                const bool hit = (lv[j] == c);
                const unsigned long long mask = __ballot(hit);
                const int below = __popcll(mask & ((1ull << ln) - 1ull));
                const int slot = cnt + below;
                if (hit && slot < MMAX) rlw[wv][slot] = wv * 2048 + it * 256 + ln * 4 + j;
                cnt += __popcll(mask);
            }
        }
        if (ln == 0) cntw[wv] = cnt;
    }
    __syncthreads();
    const int c0 = cntw[0], c1 = cntw[1], c2 = cntw[2], c3 = cntw[3];
    const int total = c0 + c1 + c2 + c3;
    const int m = total < MMAX ? total : MMAX;
    if (m == 0) return;
    const bool row_valid = (total >= 2) && (total < B_ROWS);
    {
        const int offs = (wv > 0 ? c0 : 0) + (wv > 1 ? c1 : 0) + (wv > 2 ? c2 : 0);
        const int mycnt = cntw[wv] < MMAX ? cntw[wv] : MMAX;
        if (ln < mycnt) {
            const int slot = offs + ln;
            if (slot < m) rl[slot] = rlw[wv][ln];
        }
    }
    __syncthreads();

    const unsigned int* fbp = (const unsigned int*)fb_;
    for (int i = wv; i < m; i += 4) {
        const int r = rl[i];
        const int g = ((r >> 4) * 4 + (ln >> 4)) * 256 + ((ln >> 2) & 3) * 64 +
                      (r & 15) * 4 + (ln & 3);
        F[i][ln] = fbp[g];
    }
    __syncthreads();

    for (int i = wv; i < m; i += 4) {
        float s = 0.f;
        if (ln < m) {
            #pragma unroll 8
            for (int k = 0; k < 64; ++k) {
                const unsigned int wi = F[i][k], wj = F[ln][k];
                const float li = __uint_as_float(wi << 16);
                const float hi = __uint_as_float(wi & 0xffff0000u);
                const float lj = __uint_as_float(wj << 16);
                const float hj = __uint_as_float(wj & 0xffff0000u);
                s = fmaf(li, lj, s);
                s = fmaf(hi, hj, s);
            }
        }
        const bool act = (ln < m) && (ln != i);
        const float up = 1.25f - s;
        const float lp = act ? G2 * fmaxf(up, 0.f) * (up - 0.5f) : -1e30f;
        const float un = s + 0.25f;
        const float lnn = act ? G2 * fmaxf(un, 0.f) * (un - 0.5f) : -1e30f;
        float Mp = lp, Mn = lnn;
        #pragma unroll
        for (int d = 1; d < 64; d <<= 1) {
            Mp = fmaxf(Mp, __shfl_xor(Mp, d));
            Mn = fmaxf(Mn, __shfl_xor(Mn, d));
        }
        float Sp = act ? __builtin_amdgcn_exp2f(lp - Mp) : 0.f;
        float Sn = act ? __builtin_amdgcn_exp2f(lnn - Mn) : 0.f;
        #pragma unroll
        for (int d = 1; d < 64; d <<= 1) { Sp += __shfl_xor(Sp, d); Sn += __shfl_xor(Sn, d); }
        if (ln == 0) {
            const int row = rl[i];
            lse2_p[row]    = row_valid ? (Mp + __builtin_amdgcn_logf(Sp)) : -1e30f;
            lse2_same[row] = row_valid ? (Mn + __builtin_amdgcn_logf(Sn)) : -1e30f;
        }
    }
}

// ============ K3: finalize — parallel raw-sum, one log2 per row =============
__global__ __launch_bounds__(256) void finalize_k(const float* __restrict__ PR,
                                                  const float* __restrict__ lse2_p,
                                                  const float* __restrict__ lse2_same,
                                                  int* __restrict__ ctrl,
                                                  float* __restrict__ out) {
    const int r = blockIdx.x * 256 + threadIdx.x;
    float local = 0.f; int c = 0;
    const float lp2 = lse2_p[r];
    if (lp2 > -1e29f) {
        float pa = 0.f, pb = 0.f, pc = 0.f, pd = 0.f;
        #pragma unroll
        for (int s = 0; s < NSLICE; s += 4) {
            pa += PR[(s + 0) * B_ROWS + r];
            pb += PR[(s + 1) * B_ROWS + r];
            pc += PR[(s + 2) * B_ROWS + r];
            pd += PR[(s + 3) * B_ROWS + r];
        }
        const float Sa = (pa + pb) + (pc + pd);
        const float lse2_all = __builtin_amdgcn_logf(Sa) + 64.f;  // unbias
        const float d = lse2_same[r] - lse2_all;
        const float corr = __builtin_amdgcn_logf(fmaxf(1.f - __builtin_amdgcn_exp2f(d), 1e-30f));
        const float z = LN2F * (lp2 + lse2_all + corr);
        local = fmaxf(z, 0.f) + log1pf(expf(-fabsf(z)));  // stable softplus
        c = 1;
    }
    #pragma unroll
    for (int d = 1; d < 64; d <<= 1) { local += __shfl_xor(local, d); c += __shfl_xor(c, d); }
    __shared__ float wsum[4];
    __shared__ int wcnt[4];
    const int wv = threadIdx.x >> 6;
    if ((threadIdx.x & 63) == 0) { wsum[wv] = local; wcnt[wv] = c; }
    __syncthreads();
    if (threadIdx.x == 0) {
        const float ts = wsum[0] + wsum[1] + wsum[2] + wsum[3];
        const int tc = wcnt[0] + wcnt[1] + wcnt[2] + wcnt[3];
        atomicAdd((float*)&ctrl[1], ts);
        atomicAdd(&ctrl[2], tc);
        __threadfence();
        const int ticket = atomicAdd(&ctrl[0], 1);
        if (ticket == (int)gridDim.x - 1) {
            const float gs = atomicAdd((float*)&ctrl[1], 0.0f);
            const int gc = atomicAdd(&ctrl[2], 0);
            out[0] = gs / (float)(gc > 1 ? gc : 1);
        }
    }
}

// ---------------- launch ----------------------------------------------------
extern "C" void kernel_launch(void* const* d_in, const int* in_sizes, int n_in,
                              void* d_out, int out_size, void* d_ws, size_t ws_size,
                              hipStream_t stream) {
    const float* feat = (const float*)d_in[0];
    const int* label = (const int*)d_in[1];
    float* out = (float*)d_out;
    char* ws = (char*)d_ws;

    unsigned int* fbp = (unsigned int*)(ws);                  // 2 MB packed bf16
    float* PR         = (float*)(ws + (2u << 20));            // 64*8192*4 = 2 MB
    float* lse2_p     = (float*)(ws + (4u << 20));            // 32 KB
    float* lse2_same  = (float*)(ws + (4u << 20) + 32768);    // 32 KB
    int*   ctrl       = (int*)  (ws + (4u << 20) + 65536);    // 16 B

    prep_k<<<NCLS, 256, 0, stream>>>(feat, fbp, ctrl);
    mega_k<<<NPAIR + NCLS, 256, 0, stream>>>((const unsigned short*)fbp, label,
                                             PR, lse2_p, lse2_same);
    finalize_k<<<B_ROWS / 256, 256, 0, stream>>>(PR, lse2_p, lse2_same, ctrl, out);
}